// Round 1
// baseline (241.119 us; speedup 1.0000x reference)
//
#include <hip/hip_runtime.h>

// Problem constants (fixed by setup_inputs)
#define BB   8
#define NS   5
#define NQ   75
#define NG   4
#define NF   49      // nsf == nqf
#define NFP  52      // padded row count (multiple of 4 covering 49)
#define CDIM 64
#define SSTR 68      // LDS row stride (floats) for 49x64 feature tiles (16B-aligned, breaks pow2 banks)
#define KSTR 53      // LDS row stride for 49x49 kernel matrices
#define TILE_F4 784  // 49*64/4 float4 per tile
#define VPERC 15     // v per chunk in kernel_mmd_s
#define VCHUNKS 5

__device__ __forceinline__ float multi_gauss(float d2) {
    // sum_k exp(-2^k/8 * d2), k=0..4  ==  t + t^2 + t^4 + t^8 + t^16, t=exp(-d2/8)
    d2 = fmaxf(d2, 0.f);
    float e  = __expf(-0.125f * d2);
    float e2 = e * e, e4 = e2 * e2, e8 = e4 * e4, e16 = e8 * e8;
    return e + e2 + e4 + e8 + e16;
}

// ---------------------------------------------------------------------------
// Kernel 1: mmd_s[b,v,s,g] = beta^T Kss beta.  Grid = VCHUNKS*160 = 800.
// ---------------------------------------------------------------------------
__global__ __launch_bounds__(192) void kernel_mmd_s(
    const float* __restrict__ sup, const float* __restrict__ beta,
    float* __restrict__ mmd_s_arr)
{
    int blk = blockIdx.x;
    int g  = blk & 3;
    int s  = (blk >> 2) % NS;
    int b  = (blk / (NS * NG)) % BB;
    int vc = blk / (BB * NS * NG);

    __shared__ __align__(16) float S[NFP][SSTR];
    __shared__ float K[NFP][KSTR];
    __shared__ float ssq[NFP];

    int t = threadIdx.x;
    const float4* sp = (const float4*)(sup + (size_t)((b * NS + s) * NG + g) * (NF * CDIM));
    for (int k = t; k < TILE_F4; k += 192) {
        int i = k >> 4, c4 = k & 15;
        *(float4*)&S[i][c4 * 4] = sp[k];
    }
    if (t < 48) {  // zero pad rows 49..51
        int i = NF + t / 16, c4 = t % 16;
        *(float4*)&S[i][c4 * 4] = make_float4(0.f, 0.f, 0.f, 0.f);
    }
    __syncthreads();
    if (t < NFP) {
        float a = 0.f;
        for (int c = 0; c < CDIM; c += 4) {
            float4 x = *(float4*)&S[t][c];
            a += x.x * x.x + x.y * x.y + x.z * x.z + x.w * x.w;
        }
        ssq[t] = a;
    }
    __syncthreads();
    if (t < 169) {
        int ty = t / 13, tx = t - ty * 13;
        int i0 = ty * 4, j0 = tx * 4;
        float acc[4][4] = {};
        for (int c = 0; c < CDIM; c += 4) {
            float4 av[4], bv[4];
#pragma unroll
            for (int r = 0; r < 4; ++r) av[r] = *(float4*)&S[i0 + r][c];
#pragma unroll
            for (int u = 0; u < 4; ++u) bv[u] = *(float4*)&S[j0 + u][c];
#pragma unroll
            for (int r = 0; r < 4; ++r)
#pragma unroll
                for (int u = 0; u < 4; ++u)
                    acc[r][u] += av[r].x * bv[u].x + av[r].y * bv[u].y
                               + av[r].z * bv[u].z + av[r].w * bv[u].w;
        }
#pragma unroll
        for (int r = 0; r < 4; ++r)
#pragma unroll
            for (int u = 0; u < 4; ++u)
                K[i0 + r][j0 + u] = multi_gauss(ssq[i0 + r] + ssq[j0 + u] - 2.f * acc[r][u]);
    }
    __syncthreads();

    int wave = t >> 6, lane = t & 63;
    for (int vi = wave; vi < VPERC; vi += 3) {
        int v = vc * VPERC + vi;
        const float* bp = beta + (size_t)(((b * NQ + v) * NS + s) * NG + g) * NF;
        float part = 0.f;
        if (lane < NF) {
            float u = 0.f;
            for (int i = 0; i < NF; ++i) u = fmaf(bp[i], K[i][lane], u);  // bp[i]: wave-uniform s_load
            part = u * bp[lane];
        }
        for (int off = 32; off; off >>= 1) part += __shfl_down(part, off, 64);
        if (lane == 0) mmd_s_arr[((b * NQ + v) * NS + s) * NG + g] = part;
    }
}

// ---------------------------------------------------------------------------
// Kernel 2: mmd_q[b,v,s,g] = gamma^T Kqq gamma.  Grid = 8*75*4 = 2400.
// ---------------------------------------------------------------------------
__global__ __launch_bounds__(192) void kernel_mmd_q(
    const float* __restrict__ qry, const float* __restrict__ gamma,
    float* __restrict__ mmd_q_arr)
{
    int blk = blockIdx.x;
    int g  = blk & 3;
    int bv = blk >> 2;
    int v  = bv % NQ;
    int b  = bv / NQ;

    __shared__ __align__(16) float Q[NFP][SSTR];
    __shared__ float K[NFP][KSTR];
    __shared__ float qsq[NFP];

    int t = threadIdx.x;
    const float4* qp = (const float4*)(qry + (size_t)((b * NQ + v) * NG + g) * (NF * CDIM));
    for (int k = t; k < TILE_F4; k += 192) {
        int i = k >> 4, c4 = k & 15;
        *(float4*)&Q[i][c4 * 4] = qp[k];
    }
    if (t < 48) {
        int i = NF + t / 16, c4 = t % 16;
        *(float4*)&Q[i][c4 * 4] = make_float4(0.f, 0.f, 0.f, 0.f);
    }
    __syncthreads();
    if (t < NFP) {
        float a = 0.f;
        for (int c = 0; c < CDIM; c += 4) {
            float4 x = *(float4*)&Q[t][c];
            a += x.x * x.x + x.y * x.y + x.z * x.z + x.w * x.w;
        }
        qsq[t] = a;
    }
    __syncthreads();
    if (t < 169) {
        int ty = t / 13, tx = t - ty * 13;
        int i0 = ty * 4, j0 = tx * 4;
        float acc[4][4] = {};
        for (int c = 0; c < CDIM; c += 4) {
            float4 av[4], bv4[4];
#pragma unroll
            for (int r = 0; r < 4; ++r) av[r] = *(float4*)&Q[i0 + r][c];
#pragma unroll
            for (int u = 0; u < 4; ++u) bv4[u] = *(float4*)&Q[j0 + u][c];
#pragma unroll
            for (int r = 0; r < 4; ++r)
#pragma unroll
                for (int u = 0; u < 4; ++u)
                    acc[r][u] += av[r].x * bv4[u].x + av[r].y * bv4[u].y
                               + av[r].z * bv4[u].z + av[r].w * bv4[u].w;
        }
#pragma unroll
        for (int r = 0; r < 4; ++r)
#pragma unroll
            for (int u = 0; u < 4; ++u)
                K[i0 + r][j0 + u] = multi_gauss(qsq[i0 + r] + qsq[j0 + u] - 2.f * acc[r][u]);
    }
    __syncthreads();

    int wave = t >> 6, lane = t & 63;
    for (int si = wave; si < NS; si += 3) {
        const float* gp = gamma + (size_t)(((b * NQ + v) * NS + si) * NG + g) * NF;
        float part = 0.f;
        if (lane < NF) {
            float u = 0.f;
            for (int i = 0; i < NF; ++i) u = fmaf(gp[i], K[i][lane], u);
            part = u * gp[lane];
        }
        for (int off = 32; off; off >>= 1) part += __shfl_down(part, off, 64);
        if (lane == 0) mmd_q_arr[((b * NQ + v) * NS + si) * NG + g] = part;
    }
}

// ---------------------------------------------------------------------------
// Kernel 3: fused cross term + combine.  Grid = 8*75*5 = 3000, one (b,v,s) each.
// ---------------------------------------------------------------------------
__global__ __launch_bounds__(192) void mmd_cross(
    const float* __restrict__ sup, const float* __restrict__ qry,
    const float* __restrict__ beta, const float* __restrict__ gamma,
    const float* __restrict__ mmd_s_arr, const float* __restrict__ mmd_q_arr,
    float* __restrict__ out)
{
    int blk = blockIdx.x;
    int s  = blk % NS;
    int bv = blk / NS;
    int v  = bv % NQ;
    int b  = bv / NQ;

    __shared__ __align__(16) float S[NFP][SSTR];
    __shared__ __align__(16) float Q[NFP][SSTR];
    __shared__ float sb[NFP], gm[NFP], ssq[NFP], qsq[NFP];
    __shared__ float wsum[3];

    int t = threadIdx.x;
    float total = 0.f;  // meaningful on thread 0 only

    for (int g = 0; g < NG; ++g) {
        const float4* sp = (const float4*)(sup + (size_t)((b * NS + s) * NG + g) * (NF * CDIM));
        const float4* qp = (const float4*)(qry + (size_t)((b * NQ + v) * NG + g) * (NF * CDIM));
        for (int k = t; k < TILE_F4; k += 192) {
            int i = k >> 4, c4 = k & 15;
            *(float4*)&S[i][c4 * 4] = sp[k];
            *(float4*)&Q[i][c4 * 4] = qp[k];
        }
        if (t < 48) {
            int i = NF + t / 16, c4 = t % 16;
            *(float4*)&S[i][c4 * 4] = make_float4(0.f, 0.f, 0.f, 0.f);
            *(float4*)&Q[i][c4 * 4] = make_float4(0.f, 0.f, 0.f, 0.f);
        }
        const float* bp = beta  + (size_t)(((b * NQ + v) * NS + s) * NG + g) * NF;
        const float* gp = gamma + (size_t)(((b * NQ + v) * NS + s) * NG + g) * NF;
        if (t < NFP) { sb[t] = (t < NF) ? bp[t] : 0.f; gm[t] = (t < NF) ? gp[t] : 0.f; }
        __syncthreads();

        if (t < NFP) {
            float a = 0.f;
            for (int c = 0; c < CDIM; c += 4) {
                float4 x = *(float4*)&S[t][c];
                a += x.x * x.x + x.y * x.y + x.z * x.z + x.w * x.w;
            }
            ssq[t] = a;
        } else if (t >= 64 && t < 64 + NFP) {
            int j = t - 64;
            float a = 0.f;
            for (int c = 0; c < CDIM; c += 4) {
                float4 x = *(float4*)&Q[j][c];
                a += x.x * x.x + x.y * x.y + x.z * x.z + x.w * x.w;
            }
            qsq[j] = a;
        }
        __syncthreads();

        float part = 0.f;
        if (t < 169) {
            int ty = t / 13, tx = t - ty * 13;
            int i0 = ty * 4, j0 = tx * 4;
            float acc[4][4] = {};
            for (int c = 0; c < CDIM; c += 4) {
                float4 av[4], qv[4];
#pragma unroll
                for (int r = 0; r < 4; ++r) av[r] = *(float4*)&S[i0 + r][c];
#pragma unroll
                for (int u = 0; u < 4; ++u) qv[u] = *(float4*)&Q[j0 + u][c];
#pragma unroll
                for (int r = 0; r < 4; ++r)
#pragma unroll
                    for (int u = 0; u < 4; ++u)
                        acc[r][u] += av[r].x * qv[u].x + av[r].y * qv[u].y
                                   + av[r].z * qv[u].z + av[r].w * qv[u].w;
            }
#pragma unroll
            for (int r = 0; r < 4; ++r)
#pragma unroll
                for (int u = 0; u < 4; ++u) {
                    float kv = multi_gauss(ssq[i0 + r] + qsq[j0 + u] - 2.f * acc[r][u]);
                    part = fmaf(sb[i0 + r] * gm[j0 + u], kv, part);
                }
        }
        for (int off = 32; off; off >>= 1) part += __shfl_down(part, off, 64);
        int wave = t >> 6, lane = t & 63;
        if (lane == 0) wsum[wave] = part;
        __syncthreads();
        if (t == 0) {
            float msq = wsum[0] + wsum[1] + wsum[2];
            int idx4 = ((b * NQ + v) * NS + s) * NG + g;
            total += mmd_s_arr[idx4] + mmd_q_arr[idx4] - 2.f * msq;
        }
        __syncthreads();  // protect wsum + LDS tiles before next g
    }
    if (t == 0) out[blk] = 0.25f * total;
}

extern "C" void kernel_launch(void* const* d_in, const int* in_sizes, int n_in,
                              void* d_out, int out_size, void* d_ws, size_t ws_size,
                              hipStream_t stream) {
    const float* sup   = (const float*)d_in[0];
    const float* qry   = (const float*)d_in[1];
    const float* beta  = (const float*)d_in[2];
    const float* gamma = (const float*)d_in[3];
    float* out = (float*)d_out;
    float* mmd_s_arr = (float*)d_ws;            // 12000 floats
    float* mmd_q_arr = mmd_s_arr + 12000;       // 12000 floats

    kernel_mmd_s<<<VCHUNKS * BB * NS * NG, 192, 0, stream>>>(sup, beta, mmd_s_arr);
    kernel_mmd_q<<<BB * NQ * NG, 192, 0, stream>>>(qry, gamma, mmd_q_arr);
    mmd_cross<<<BB * NQ * NS, 192, 0, stream>>>(sup, qry, beta, gamma,
                                                mmd_s_arr, mmd_q_arr, out);
}